// Round 3
// baseline (379.777 us; speedup 1.0000x reference)
//
#include <hip/hip_runtime.h>
#include <math.h>

#define DIMC 1024
#define BB   8
#define LL   2048
#define ACTC 256
#define HIDC 256
#define EPSV 1e-6f
#define MROWS (BB * LL)   // 16384
#define NCHUNK 32
#define LC     64         // LL / NCHUNK

typedef __bf16 bf16x8 __attribute__((ext_vector_type(8)));
typedef float  f32x4  __attribute__((ext_vector_type(4)));

__device__ __forceinline__ unsigned short f2bf(float f) {
    union { float f; unsigned int u; } v; v.f = f;
    unsigned int u = v.u + 0x7fffu + ((v.u >> 16) & 1u);
    return (unsigned short)(u >> 16);
}
__device__ __forceinline__ float bf2f(unsigned short s) {
    union { float f; unsigned int u; } v; v.u = ((unsigned int)s) << 16;
    return v.f;
}
// inf-safe fast sigmoid/tanh on native v_exp_f32
__device__ __forceinline__ float fast_sigmoid(float x) {
    return 1.0f / (1.0f + __expf(-x));
}
__device__ __forceinline__ float fast_tanh(float x) {
    float ax = fabsf(x);
    float t = 1.0f - 2.0f / (__expf(2.0f * ax) + 1.0f);  // exp(inf)->inf -> t=1
    return copysignf(t, x);
}

// ---------------- weight convert: all 5 weights in one launch ----------------
__global__ void k_convert5(const float* __restrict__ s0, const float* __restrict__ s1,
                           const float* __restrict__ s2, const float* __restrict__ s3,
                           const float* __restrict__ s4,
                           unsigned short* __restrict__ d0, unsigned short* __restrict__ d1,
                           unsigned short* __restrict__ d2, unsigned short* __restrict__ d3,
                           unsigned short* __restrict__ d4) {
    int i = blockIdx.x * blockDim.x + threadIdx.x;  // total 3670016
    if (i < 1048576)            d0[i]           = f2bf(s0[i]);
    else if (i < 2097152)       d1[i - 1048576] = f2bf(s1[i - 1048576]);
    else if (i < 3145728)       d2[i - 2097152] = f2bf(s2[i - 2097152]);
    else if (i < 3407872)       d3[i - 3145728] = f2bf(s3[i - 3145728]);
    else if (i < 3670016)       d4[i - 3407872] = f2bf(s4[i - 3407872]);
}

// ---------------- RMSNorm: one block per row, bf16 out ----------------
__global__ __launch_bounds__(256) void k_rmsnorm(const float* __restrict__ x,
                                                 const float* __restrict__ w,
                                                 unsigned short* __restrict__ xnb) {
    int m = blockIdx.x;
    int t = threadIdx.x;
    float4 v = ((const float4*)(x + (size_t)m * DIMC))[t];
    float ss = v.x*v.x + v.y*v.y + v.z*v.z + v.w*v.w;
#pragma unroll
    for (int off = 32; off > 0; off >>= 1) ss += __shfl_down(ss, off, 64);
    __shared__ float sred[4];
    if ((t & 63) == 0) sred[t >> 6] = ss;
    __syncthreads();
    float tot = sred[0] + sred[1] + sred[2] + sred[3];
    float rinv = 1.0f / sqrtf(tot * (1.0f / DIMC) + EPSV);
    float4 wv = ((const float4*)w)[t];
    uint2 o;
    o.x = (unsigned)f2bf(wv.x * v.x * rinv) | ((unsigned)f2bf(wv.y * v.y * rinv) << 16);
    o.y = (unsigned)f2bf(wv.z * v.z * rinv) | ((unsigned)f2bf(wv.w * v.w * rinv) << 16);
    ((uint2*)(xnb + (size_t)m * DIMC))[t] = o;
}

// ---------------- depthwise conv K=5, zero-pad, bf16 in/out ----------------
__global__ __launch_bounds__(256) void k_dwconv(const unsigned short* __restrict__ xnb,
                                                const float* __restrict__ dww,
                                                const float* __restrict__ dwb,
                                                unsigned short* __restrict__ xc) {
    int m = blockIdx.x;          // b*LL + l
    int l = m & (LL - 1);
    int t = threadIdx.x;         // channel group of 4
    int c0 = t * 4;
    float wgt[4][5];
#pragma unroll
    for (int j = 0; j < 4; ++j)
#pragma unroll
        for (int k = 0; k < 5; ++k) wgt[j][k] = dww[(c0 + j) * 5 + k];
    float4 bv = ((const float4*)dwb)[t];
    float acc[4] = {bv.x, bv.y, bv.z, bv.w};
#pragma unroll
    for (int k = 0; k < 5; ++k) {
        int ll = l + k - 2;
        if (ll < 0 || ll >= LL) continue;
        uint2 rv = ((const uint2*)(xnb + (size_t)(m + k - 2) * DIMC))[t];
        acc[0] += bf2f((unsigned short)(rv.x & 0xffff)) * wgt[0][k];
        acc[1] += bf2f((unsigned short)(rv.x >> 16))    * wgt[1][k];
        acc[2] += bf2f((unsigned short)(rv.y & 0xffff)) * wgt[2][k];
        acc[3] += bf2f((unsigned short)(rv.y >> 16))    * wgt[3][k];
    }
    uint2 o;
    o.x = (unsigned)f2bf(acc[0]) | ((unsigned)f2bf(acc[1]) << 16);
    o.y = (unsigned)f2bf(acc[2]) | ((unsigned)f2bf(acc[3]) << 16);
    ((uint2*)(xc + (size_t)m * DIMC))[t] = o;
}

// ---------------- chunked parallel scan ----------------
__global__ __launch_bounds__(256) void k_scan_a(const unsigned short* __restrict__ xnb,
                                                const float* __restrict__ alpha,
                                                const float* __restrict__ beta,
                                                float* __restrict__ F) {
    int blk = blockIdx.x;        // b*NCHUNK + k
    int b = blk >> 5, k = blk & (NCHUNK - 1);
    int c = threadIdx.x;
    float a = alpha[c], bt = beta[c];
    const unsigned short* p = xnb + ((size_t)(b * LL + k * LC)) * DIMC + c;
    float h = 0.0f;
    for (int l = 0; l < LC; ++l) h = a * h + bt * bf2f(p[(size_t)l * DIMC]);
    F[(size_t)blk * ACTC + c] = h;
}
__global__ __launch_bounds__(256) void k_scan_b(const float* __restrict__ alpha,
                                                const float* __restrict__ F,
                                                float* __restrict__ Cv) {
    int b = blockIdx.x;
    int c = threadIdx.x;
    float a = alpha[c];
    float aL = a;
#pragma unroll
    for (int i = 0; i < 6; ++i) aL *= aL;   // a^64
    float T = 0.0f;
    for (int k = 0; k < NCHUNK; ++k) {
        size_t idx = ((size_t)b * NCHUNK + k) * ACTC + c;
        Cv[idx] = T;
        T = F[idx] + aL * T;
    }
}
__global__ __launch_bounds__(256) void k_scan_c(const unsigned short* __restrict__ xnb,
                                                const float* __restrict__ alpha,
                                                const float* __restrict__ beta,
                                                const float* __restrict__ Cv,
                                                unsigned short* __restrict__ hs) {
    int blk = blockIdx.x;
    int b = blk >> 5, k = blk & (NCHUNK - 1);
    int c = threadIdx.x;
    float a = alpha[c], bt = beta[c];
    const unsigned short* p = xnb + ((size_t)(b * LL + k * LC)) * DIMC + c;
    unsigned short*       q = hs  + ((size_t)(b * LL + k * LC)) * ACTC + c;
    float h = Cv[(size_t)blk * ACTC + c];
    for (int l = 0; l < LC; ++l) {
        h = a * h + bt * bf2f(p[(size_t)l * DIMC]);
        q[(size_t)l * ACTC] = f2bf(h);
    }
}

// ---------------- legacy 128x128 MFMA GEMM (MODE 0 and 3) ----------------
#define TM 128
#define TN 128
#define BK 64

#define GLOAD_LDS(gp, lp) \
    __builtin_amdgcn_global_load_lds((const __attribute__((address_space(1))) unsigned int*)(gp), \
                                     (__attribute__((address_space(3))) unsigned int*)(lp), 16, 0, 0)

template<int MODE>
__global__ __launch_bounds__(256, (MODE == 1) ? 2 : 4) void k_gemm(
        const unsigned short* __restrict__ A,
        const unsigned short* __restrict__ B0,
        const unsigned short* __restrict__ B1,
        const float* __restrict__ bias0,
        const float* __restrict__ bias1,
        const unsigned short* __restrict__ add0,
        const unsigned short* __restrict__ add1,
        const float* __restrict__ addf,
        float* __restrict__ outf,
        unsigned short* __restrict__ outb,
        int M, int N, int K)
{
    constexpr int LDSB = (MODE == 1) ? 49152 : 32768;
    __shared__ __align__(16) char lds[LDSB];
    unsigned short* sA  = (unsigned short*)lds;
    unsigned short* sB0 = (unsigned short*)(lds + 16384);
    unsigned short* sB1 = (unsigned short*)(lds + 32768);

    int nx = gridDim.x;
    int bid = blockIdx.y * nx + blockIdx.x;
    int xcd = bid & 7, s = bid >> 3;
    int colt = s % nx, rowgrp = s / nx;
    int m0 = (rowgrp * 8 + xcd) * TM;
    int n0 = colt * TN;

    int t = threadIdx.x;
    int w = t >> 6, lane = t & 63;
    int wm = (w >> 1) * 64, wn = (w & 1) * 64;
    int quad = lane >> 4, lm = lane & 15;
    int lm7 = lm & 7;

    f32x4 zero = {0.f, 0.f, 0.f, 0.f};
    f32x4 acc0[4][4];
    f32x4 acc1[(MODE == 1) ? 4 : 1][(MODE == 1) ? 4 : 1];
#pragma unroll
    for (int i = 0; i < 4; ++i)
#pragma unroll
        for (int j = 0; j < 4; ++j) acc0[i][j] = zero;
    if constexpr (MODE == 1) {
#pragma unroll
        for (int i = 0; i < 4; ++i)
#pragma unroll
            for (int j = 0; j < 4; ++j) acc1[i][j] = zero;
    }

    for (int k0 = 0; k0 < K; k0 += BK) {
        __syncthreads();
#pragma unroll
        for (int c = 0; c < 4; ++c) {
            int i = t + c * 256;
            int r = i >> 3;
            int sc = ((i & 7) ^ (r & 7)) << 3;   // swizzled source k-group
            GLOAD_LDS(A  + (size_t)(m0 + r) * K + k0 + sc, sA  + i * 8);
            GLOAD_LDS(B0 + (size_t)(n0 + r) * K + k0 + sc, sB0 + i * 8);
            if constexpr (MODE == 1)
                GLOAD_LDS(B1 + (size_t)(n0 + r) * K + k0 + sc, sB1 + i * 8);
        }
        __syncthreads();

#pragma unroll
        for (int ks = 0; ks < BK; ks += 32) {
            int cgb = ks >> 3;   // 0 or 4
            bf16x8 af[4], b0f[4];
#pragma unroll
            for (int i = 0; i < 4; ++i) {
                int sg = ((cgb + quad) ^ lm7) << 3;
                af[i]  = *(const bf16x8*)(sA  + (wm + i * 16 + lm) * BK + sg);
                b0f[i] = *(const bf16x8*)(sB0 + (wn + i * 16 + lm) * BK + sg);
            }
            if constexpr (MODE == 1) {
                bf16x8 b1f[4];
#pragma unroll
                for (int i = 0; i < 4; ++i)
                    b1f[i] = *(const bf16x8*)(sB1 + (wn + i * 16 + lm) * BK + (((cgb + quad) ^ lm7) << 3));
#pragma unroll
                for (int mi = 0; mi < 4; ++mi)
#pragma unroll
                    for (int ni = 0; ni < 4; ++ni) {
                        acc0[mi][ni] = __builtin_amdgcn_mfma_f32_16x16x32_bf16(af[mi], b0f[ni], acc0[mi][ni], 0, 0, 0);
                        acc1[mi][ni] = __builtin_amdgcn_mfma_f32_16x16x32_bf16(af[mi], b1f[ni], acc1[mi][ni], 0, 0, 0);
                    }
            } else {
#pragma unroll
                for (int mi = 0; mi < 4; ++mi)
#pragma unroll
                    for (int ni = 0; ni < 4; ++ni)
                        acc0[mi][ni] = __builtin_amdgcn_mfma_f32_16x16x32_bf16(af[mi], b0f[ni], acc0[mi][ni], 0, 0, 0);
            }
        }
    }

    __syncthreads();
    if constexpr (MODE == 3) {
        float* sO = (float*)lds;
#pragma unroll
        for (int half = 0; half < 2; ++half) {
            if (wm == half * 64) {
#pragma unroll
                for (int mi = 0; mi < 4; ++mi) {
#pragma unroll
                    for (int ni = 0; ni < 4; ++ni) {
                        int nl = wn + ni * 16 + lm;
                        float bn = bias0[n0 + nl];
#pragma unroll
                        for (int j = 0; j < 4; ++j) {
                            int mloc = mi * 16 + quad * 4 + j;   // 0..63
                            sO[mloc * TN + nl] = acc0[mi][ni][j] + bn;
                        }
                    }
                }
            }
            __syncthreads();
#pragma unroll
            for (int c = 0; c < 8; ++c) {
                int i = t + c * 256;
                int r = i >> 5, c4 = (i & 31) << 2;
                int m = m0 + half * 64 + r, n = n0 + c4;
                float4 v  = *(float4*)(sO + r * TN + c4);
                uint2  ab = *(const uint2*)(add0 + (size_t)m * N + n);
                float4 xf = *(const float4*)(addf + (size_t)m * N + n);
                float4 o;
                o.x = v.x + bf2f((unsigned short)(ab.x & 0xffff)) + xf.x;
                o.y = v.y + bf2f((unsigned short)(ab.x >> 16))    + xf.y;
                o.z = v.z + bf2f((unsigned short)(ab.y & 0xffff)) + xf.z;
                o.w = v.w + bf2f((unsigned short)(ab.y >> 16))    + xf.w;
                *(float4*)(outf + (size_t)m * N + n) = o;
            }
            __syncthreads();
        }
    } else {
        unsigned short* sO = (unsigned short*)lds;
#pragma unroll
        for (int mi = 0; mi < 4; ++mi) {
#pragma unroll
            for (int ni = 0; ni < 4; ++ni) {
                int nl = wn + ni * 16 + lm;
                int n  = n0 + nl;
                float bn = bias0[n];
                float bn1 = (MODE == 1) ? bias1[n] : 0.0f;
#pragma unroll
                for (int j = 0; j < 4; ++j) {
                    int ml = wm + mi * 16 + quad * 4 + j;
                    float v = acc0[mi][ni][j];
                    float r;
                    if constexpr (MODE == 0) {
                        r = v + bn;
                    } else if constexpr (MODE == 1) {
                        float u1 = v + bn;
                        float u2 = acc1[mi][ni][j] + bn1;
                        r = fast_sigmoid(u1) * fast_tanh(u2);
                    } else { // MODE 2
                        float u = v + bn;
                        r = 0.5f * u * (1.0f + erff(u * 0.70710678118654752f));
                    }
                    sO[ml * TN + nl] = f2bf(r);
                }
            }
        }
        __syncthreads();
#pragma unroll
        for (int c = 0; c < 8; ++c) {
            int i = t + c * 256;
            int r = i >> 4, c8 = (i & 15) << 3;
            int m = m0 + r, n = n0 + c8;
            uint4 g = *(uint4*)(sO + r * TN + c8);
            if constexpr (MODE == 2) {
                *(uint4*)(outb + (size_t)m * N + n) = g;
            } else {
                uint4 av;
                if constexpr (MODE == 0) {
                    av = (n0 < ACTC) ? *(const uint4*)(add0 + (size_t)m * ACTC + n)
                                     : *(const uint4*)(add1 + (size_t)m * DIMC + n);
                } else {
                    av = *(const uint4*)(add0 + (size_t)m * N + n);
                }
                unsigned* gp = (unsigned*)&g;
                unsigned* ap = (unsigned*)&av;
                uint4 o;
                unsigned* op = (unsigned*)&o;
#pragma unroll
                for (int q = 0; q < 4; ++q) {
                    float lo = bf2f((unsigned short)(gp[q] & 0xffff)) + bf2f((unsigned short)(ap[q] & 0xffff));
                    float hi = bf2f((unsigned short)(gp[q] >> 16))    + bf2f((unsigned short)(ap[q] >> 16));
                    op[q] = (unsigned)f2bf(lo) | ((unsigned)f2bf(hi) << 16);
                }
                *(uint4*)(outb + (size_t)m * N + n) = o;
            }
        }
    }
}

// ---------------- 128x64-tile GEMM (MODE 1 and 2): occupancy experiment ----------------
// R3 theory: all three ~86us gemm1 variants shared 8 waves/CU with tight coupling
// (legacy: 2 blocks/CU forced by dual-acc VGPRs; 8-phase: 1 big block, lockstep
// barriers). m114: the m97-structure's throughput comes from IMPLICIT overlap of
// ~3 independent blocks/CU. TN=64 halves the accumulator footprint (64 f32), so
// launch_bounds(256,3) fits without spilling -> 3 blocks/CU, 12 waves/CU, and a
// 2048-block grid. Same proven 2-phase structure; only tile geometry changes.
// MODE2 gains even more: its TN=128 grid was 256 blocks = 1 block/CU = 4 waves/CU.
template<int MODE>
__global__ __launch_bounds__(256, (MODE == 1) ? 3 : 4) void k_gemm64(
        const unsigned short* __restrict__ A,
        const unsigned short* __restrict__ B0,
        const unsigned short* __restrict__ B1,
        const float* __restrict__ bias0,
        const float* __restrict__ bias1,
        const unsigned short* __restrict__ add0,
        unsigned short* __restrict__ outb,
        int M, int N, int K)
{
    constexpr int LDSB = (MODE == 1) ? 32768 : 24576;
    __shared__ __align__(16) char lds[LDSB];
    unsigned short* sA  = (unsigned short*)lds;                  // 128x64 = 16KB
    unsigned short* sB0 = (unsigned short*)(lds + 16384);        // 64x64  =  8KB
    unsigned short* sB1 = (unsigned short*)(lds + 24576);        // 64x64  =  8KB (MODE1)

    int nx = gridDim.x;
    int bid = blockIdx.y * nx + blockIdx.x;
    int xcd = bid & 7, s = bid >> 3;
    int colt = s % nx, rowgrp = s / nx;
    int m0 = (rowgrp * 8 + xcd) * TM;
    int n0 = colt * 64;

    int t = threadIdx.x;
    int w = t >> 6, lane = t & 63;
    int wm = (w >> 1) * 64, wn = (w & 1) * 32;   // 2x2 wave grid: 64 rows x 32 cols each
    int quad = lane >> 4, lm = lane & 15;
    int lm7 = lm & 7;

    f32x4 zero = {0.f, 0.f, 0.f, 0.f};
    f32x4 acc0[4][2];
    f32x4 acc1[(MODE == 1) ? 4 : 1][(MODE == 1) ? 2 : 1];
#pragma unroll
    for (int i = 0; i < 4; ++i)
#pragma unroll
        for (int j = 0; j < 2; ++j) acc0[i][j] = zero;
    if constexpr (MODE == 1) {
#pragma unroll
        for (int i = 0; i < 4; ++i)
#pragma unroll
            for (int j = 0; j < 2; ++j) acc1[i][j] = zero;
    }

    for (int k0 = 0; k0 < K; k0 += BK) {
        __syncthreads();
#pragma unroll
        for (int c = 0; c < 4; ++c) {            // A: 128 rows, 4 rounds
            int i = t + c * 256;
            int r = i >> 3;
            int sc = ((i & 7) ^ (r & 7)) << 3;
            GLOAD_LDS(A + (size_t)(m0 + r) * K + k0 + sc, sA + i * 8);
        }
#pragma unroll
        for (int c = 0; c < 2; ++c) {            // B: 64 rows, 2 rounds each
            int i = t + c * 256;
            int r = i >> 3;
            int sc = ((i & 7) ^ (r & 7)) << 3;
            GLOAD_LDS(B0 + (size_t)(n0 + r) * K + k0 + sc, sB0 + i * 8);
            if constexpr (MODE == 1)
                GLOAD_LDS(B1 + (size_t)(n0 + r) * K + k0 + sc, sB1 + i * 8);
        }
        __syncthreads();

#pragma unroll
        for (int ks = 0; ks < BK; ks += 32) {
            int cgb = ks >> 3;   // 0 or 4
            int sg = ((cgb + quad) ^ lm7) << 3;
            bf16x8 af[4], b0f[2];
#pragma unroll
            for (int i = 0; i < 4; ++i)
                af[i] = *(const bf16x8*)(sA + (wm + i * 16 + lm) * BK + sg);
#pragma unroll
            for (int i = 0; i < 2; ++i)
                b0f[i] = *(const bf16x8*)(sB0 + (wn + i * 16 + lm) * BK + sg);
            if constexpr (MODE == 1) {
                bf16x8 b1f[2];
#pragma unroll
                for (int i = 0; i < 2; ++i)
                    b1f[i] = *(const bf16x8*)(sB1 + (wn + i * 16 + lm) * BK + sg);
#pragma unroll
                for (int mi = 0; mi < 4; ++mi)
#pragma unroll
                    for (int ni = 0; ni < 2; ++ni) {
                        acc0[mi][ni] = __builtin_amdgcn_mfma_f32_16x16x32_bf16(af[mi], b0f[ni], acc0[mi][ni], 0, 0, 0);
                        acc1[mi][ni] = __builtin_amdgcn_mfma_f32_16x16x32_bf16(af[mi], b1f[ni], acc1[mi][ni], 0, 0, 0);
                    }
            } else {
#pragma unroll
                for (int mi = 0; mi < 4; ++mi)
#pragma unroll
                    for (int ni = 0; ni < 2; ++ni)
                        acc0[mi][ni] = __builtin_amdgcn_mfma_f32_16x16x32_bf16(af[mi], b0f[ni], acc0[mi][ni], 0, 0, 0);
            }
        }
    }

    // epilogue: acc -> bf16 LDS pack [128][64] -> coalesced store (+ residual add)
    __syncthreads();
    unsigned short* sO = (unsigned short*)lds;
#pragma unroll
    for (int mi = 0; mi < 4; ++mi) {
#pragma unroll
        for (int ni = 0; ni < 2; ++ni) {
            int nl = wn + ni * 16 + lm;
            int n  = n0 + nl;
            float bn = bias0[n];
            float bn1 = (MODE == 1) ? bias1[n] : 0.0f;
#pragma unroll
            for (int j = 0; j < 4; ++j) {
                int ml = wm + mi * 16 + quad * 4 + j;
                float r;
                if constexpr (MODE == 1) {
                    float u1 = acc0[mi][ni][j] + bn;
                    float u2 = acc1[mi][ni][j] + bn1;
                    r = fast_sigmoid(u1) * fast_tanh(u2);
                } else { // MODE 2
                    float u = acc0[mi][ni][j] + bn;
                    r = 0.5f * u * (1.0f + erff(u * 0.70710678118654752f));
                }
                sO[ml * 64 + nl] = f2bf(r);
            }
        }
    }
    __syncthreads();
#pragma unroll
    for (int c = 0; c < 4; ++c) {
        int i = t + c * 256;
        int r = i >> 3, c8 = (i & 7) << 3;
        int m = m0 + r, n = n0 + c8;
        uint4 g = *(uint4*)(sO + r * 64 + c8);
        if constexpr (MODE == 2) {
            *(uint4*)(outb + (size_t)m * N + n) = g;
        } else {
            uint4 av = *(const uint4*)(add0 + (size_t)m * N + n);
            unsigned* gp = (unsigned*)&g;
            unsigned* ap = (unsigned*)&av;
            uint4 o;
            unsigned* op = (unsigned*)&o;
#pragma unroll
            for (int q = 0; q < 4; ++q) {
                float lo = bf2f((unsigned short)(gp[q] & 0xffff)) + bf2f((unsigned short)(ap[q] & 0xffff));
                float hi = bf2f((unsigned short)(gp[q] >> 16))    + bf2f((unsigned short)(ap[q] >> 16));
                op[q] = (unsigned)f2bf(lo) | ((unsigned)f2bf(hi) << 16);
            }
            *(uint4*)(outb + (size_t)m * N + n) = o;
        }
    }
}

extern "C" void kernel_launch(void* const* d_in, const int* in_sizes, int n_in,
                              void* d_out, int out_size, void* d_ws, size_t ws_size,
                              hipStream_t stream) {
    (void)in_sizes; (void)n_in; (void)out_size; (void)ws_size;
    const float* x      = (const float*)d_in[0];
    const float* norm_w = (const float*)d_in[1];
    const float* dw_w   = (const float*)d_in[2];
    const float* dw_b   = (const float*)d_in[3];
    const float* pw_w   = (const float*)d_in[4];
    const float* pw_b   = (const float*)d_in[5];
    const float* alpha  = (const float*)d_in[6];
    const float* beta   = (const float*)d_in[7];
    const float* W1_w   = (const float*)d_in[8];
    const float* W1_b   = (const float*)d_in[9];
    const float* W2_w   = (const float*)d_in[10];
    const float* W2_b   = (const float*)d_in[11];
    const float* down_w = (const float*)d_in[12];
    const float* down_b = (const float*)d_in[13];
    const float* up_w   = (const float*)d_in[14];
    const float* up_b   = (const float*)d_in[15];

    char* ws = (char*)d_ws;
    unsigned short* xnb  = (unsigned short*)(ws);
    unsigned short* xc   = (unsigned short*)(ws + 33554432ull);
    unsigned short* hs   = (unsigned short*)(ws + 67108864ull);
    unsigned short* y1b  = (unsigned short*)(ws + 75497472ull);
    unsigned short* y2b  = (unsigned short*)(ws + 109051904ull);
    unsigned short* gact = (unsigned short*)(ws + 142606336ull);
    unsigned short* wpw  = (unsigned short*)(ws + 150994944ull);
    unsigned short* w1b  = wpw + 1048576;
    unsigned short* w2b  = w1b + 1048576;
    unsigned short* wdn  = w2b + 1048576;
    unsigned short* wup  = wdn + 262144;
    float*          Fb   = (float*)(ws + 159383552ull);
    float*          Cb   = (float*)(ws + 159383552ull + 262144ull);

    k_convert5<<<14336, 256, 0, stream>>>(pw_w, W1_w, W2_w, down_w, up_w,
                                          wpw, w1b, w2b, wdn, wup);

    k_rmsnorm<<<MROWS, 256, 0, stream>>>(x, norm_w, xnb);
    k_dwconv <<<MROWS, 256, 0, stream>>>(xnb, dw_w, dw_b, xc);

    k_scan_a<<<BB * NCHUNK, ACTC, 0, stream>>>(xnb, alpha, beta, Fb);
    k_scan_b<<<BB, ACTC, 0, stream>>>(alpha, Fb, Cb);
    k_scan_c<<<BB * NCHUNK, ACTC, 0, stream>>>(xnb, alpha, beta, Cb, hs);

    dim3 g1(DIMC / TN, MROWS / TM);          // MODE0: (8,128) = 1024 blocks
    dim3 g1b(DIMC / 64, MROWS / TM);         // MODE1: (16,128) = 2048 blocks
    dim3 g2b(HIDC / 64, MROWS / TM);         // MODE2: (4,128)  = 512 blocks
    k_gemm<0><<<g1, 256, 0, stream>>>(xc, wpw, nullptr, pw_b, nullptr, hs, xnb, nullptr, nullptr, y1b, MROWS, DIMC, DIMC);
    k_gemm64<1><<<g1b, 256, 0, stream>>>(y1b, w1b, w2b, W1_b, W2_b, y1b, y2b, MROWS, DIMC, DIMC);
    k_gemm64<2><<<g2b, 256, 0, stream>>>(y2b, wdn, nullptr, down_b, nullptr, nullptr, gact, MROWS, HIDC, DIMC);
    k_gemm<3><<<g1, 256, 0, stream>>>(gact, wup, nullptr, up_b, nullptr, y2b, nullptr, x, (float*)d_out, nullptr, MROWS, DIMC, HIDC);
}

// Round 4
// 372.569 us; speedup vs baseline: 1.0193x; 1.0193x over previous
//
#include <hip/hip_runtime.h>
#include <math.h>

#define DIMC 1024
#define BB   8
#define LL   2048
#define ACTC 256
#define HIDC 256
#define EPSV 1e-6f
#define MROWS (BB * LL)   // 16384
#define NCHUNK 32
#define LC     64         // LL / NCHUNK

typedef __bf16 bf16x8 __attribute__((ext_vector_type(8)));
typedef float  f32x4  __attribute__((ext_vector_type(4)));

__device__ __forceinline__ unsigned short f2bf(float f) {
    union { float f; unsigned int u; } v; v.f = f;
    unsigned int u = v.u + 0x7fffu + ((v.u >> 16) & 1u);
    return (unsigned short)(u >> 16);
}
__device__ __forceinline__ float bf2f(unsigned short s) {
    union { float f; unsigned int u; } v; v.u = ((unsigned int)s) << 16;
    return v.f;
}
// inf-safe fast sigmoid/tanh on native v_exp_f32
__device__ __forceinline__ float fast_sigmoid(float x) {
    return 1.0f / (1.0f + __expf(-x));
}
__device__ __forceinline__ float fast_tanh(float x) {
    float ax = fabsf(x);
    float t = 1.0f - 2.0f / (__expf(2.0f * ax) + 1.0f);  // exp(inf)->inf -> t=1
    return copysignf(t, x);
}

// ---------------- weight convert: pw, W1/W2 (row-interleaved), down, up ----------------
// w12[2n] = W1[n], w12[2n+1] = W2[n]  -> GLU GEMM becomes single-B with N=2048;
// pair (2q, 2q+1) of output cols resolves to one GLU output col q in the epilogue.
__global__ void k_convert5(const float* __restrict__ s0, const float* __restrict__ s1,
                           const float* __restrict__ s2, const float* __restrict__ s3,
                           const float* __restrict__ s4,
                           unsigned short* __restrict__ d0, unsigned short* __restrict__ d12,
                           unsigned short* __restrict__ d3, unsigned short* __restrict__ d4) {
    int i = blockIdx.x * blockDim.x + threadIdx.x;  // total 3670016
    if (i < 1048576) {
        d0[i] = f2bf(s0[i]);
    } else if (i < 2097152) {
        int j = i - 1048576; int n = j >> 10, kk = j & 1023;
        d12[(size_t)(n * 2) * 1024 + kk] = f2bf(s1[j]);
    } else if (i < 3145728) {
        int j = i - 2097152; int n = j >> 10, kk = j & 1023;
        d12[(size_t)(n * 2 + 1) * 1024 + kk] = f2bf(s2[j]);
    } else if (i < 3407872) {
        d3[i - 3145728] = f2bf(s3[i - 3145728]);
    } else if (i < 3670016) {
        d4[i - 3407872] = f2bf(s4[i - 3407872]);
    }
}

// ---------------- fused RMSNorm + depthwise conv (strip of 32 rows + 2-row halo) ----------------
// Pass 1: wave-per-row rms (butterfly shfl, no barriers), xn -> LDS (+ global xnb for
// owned rows). OOR halo rows are written as exact zeros -> zero-padding is free in pass 2.
// Pass 2: K=5 conv reading xn from LDS only; writes xc.
// Saves: dwconv's 5x global re-read of xnb + one kernel launch.
__global__ __launch_bounds__(256, 2) void k_normconv(
        const float* __restrict__ x, const float* __restrict__ w,
        const float* __restrict__ dww, const float* __restrict__ dwb,
        unsigned short* __restrict__ xnb, unsigned short* __restrict__ xc) {
    __shared__ unsigned short sxn[36 * 1024];   // 72 KiB: rows l0-2 .. l0+33
    int blk = blockIdx.x;
    int b = blk >> 6, s = blk & 63;
    int l0 = s * 32;
    int t = threadIdx.x;
    int lane = t & 63, wid = t >> 6;

    float4 nw[4];
#pragma unroll
    for (int j = 0; j < 4; ++j) nw[j] = ((const float4*)w)[j * 64 + lane];

    for (int rr = wid; rr < 36; rr += 4) {
        int l = l0 - 2 + rr;
        bool inr = (l >= 0 && l < LL);
        float4 v[4];
#pragma unroll
        for (int j = 0; j < 4; ++j) { v[j].x = 0.f; v[j].y = 0.f; v[j].z = 0.f; v[j].w = 0.f; }
        if (inr) {
            const float4* xp = (const float4*)(x + ((size_t)b * LL + l) * DIMC);
#pragma unroll
            for (int j = 0; j < 4; ++j) v[j] = xp[j * 64 + lane];
        }
        float ss = 0.f;
#pragma unroll
        for (int j = 0; j < 4; ++j)
            ss += v[j].x * v[j].x + v[j].y * v[j].y + v[j].z * v[j].z + v[j].w * v[j].w;
#pragma unroll
        for (int off = 1; off < 64; off <<= 1) ss += __shfl_xor(ss, off, 64);
        float rinv = 1.0f / sqrtf(ss * (1.0f / DIMC) + EPSV);
#pragma unroll
        for (int j = 0; j < 4; ++j) {
            uint2 o;
            o.x = (unsigned)f2bf(nw[j].x * v[j].x * rinv) | ((unsigned)f2bf(nw[j].y * v[j].y * rinv) << 16);
            o.y = (unsigned)f2bf(nw[j].z * v[j].z * rinv) | ((unsigned)f2bf(nw[j].w * v[j].w * rinv) << 16);
            ((uint2*)(sxn + rr * 1024))[j * 64 + lane] = o;
            if (inr && rr >= 2 && rr < 34)
                ((uint2*)(xnb + ((size_t)b * LL + l) * DIMC))[j * 64 + lane] = o;
        }
    }
    __syncthreads();

    float wgt[4][5];
    int c0 = t * 4;
#pragma unroll
    for (int j = 0; j < 4; ++j)
#pragma unroll
        for (int k = 0; k < 5; ++k) wgt[j][k] = dww[(c0 + j) * 5 + k];
    float4 bv = ((const float4*)dwb)[t];
    for (int r = 0; r < 32; ++r) {
        float acc[4] = {bv.x, bv.y, bv.z, bv.w};
#pragma unroll
        for (int k = 0; k < 5; ++k) {
            uint2 rv = ((const uint2*)(sxn + (r + k) * 1024))[t];
            acc[0] += bf2f((unsigned short)(rv.x & 0xffff)) * wgt[0][k];
            acc[1] += bf2f((unsigned short)(rv.x >> 16))    * wgt[1][k];
            acc[2] += bf2f((unsigned short)(rv.y & 0xffff)) * wgt[2][k];
            acc[3] += bf2f((unsigned short)(rv.y >> 16))    * wgt[3][k];
        }
        uint2 o;
        o.x = (unsigned)f2bf(acc[0]) | ((unsigned)f2bf(acc[1]) << 16);
        o.y = (unsigned)f2bf(acc[2]) | ((unsigned)f2bf(acc[3]) << 16);
        ((uint2*)(xc + ((size_t)b * LL + l0 + r) * DIMC))[t] = o;
    }
}

// ---------------- chunked parallel scan (carry folded into pass c) ----------------
__global__ __launch_bounds__(256) void k_scan_a(const unsigned short* __restrict__ xnb,
                                                const float* __restrict__ alpha,
                                                const float* __restrict__ beta,
                                                float* __restrict__ F) {
    int blk = blockIdx.x;        // b*NCHUNK + k
    int b = blk >> 5, k = blk & (NCHUNK - 1);
    int c = threadIdx.x;
    float a = alpha[c], bt = beta[c];
    const unsigned short* p = xnb + ((size_t)(b * LL + k * LC)) * DIMC + c;
    float h = 0.0f;
    for (int l = 0; l < LC; ++l) h = a * h + bt * bf2f(p[(size_t)l * DIMC]);
    F[(size_t)blk * ACTC + c] = h;
}
__global__ __launch_bounds__(256) void k_scan_c(const unsigned short* __restrict__ xnb,
                                                const float* __restrict__ alpha,
                                                const float* __restrict__ beta,
                                                const float* __restrict__ F,
                                                unsigned short* __restrict__ hs) {
    int blk = blockIdx.x;
    int b = blk >> 5, k = blk & (NCHUNK - 1);
    int c = threadIdx.x;
    float a = alpha[c], bt = beta[c];
    float aL = a;
#pragma unroll
    for (int i = 0; i < 6; ++i) aL *= aL;   // a^64
    float T = 0.0f;
    for (int j = 0; j < k; ++j)             // recompute chunk carry (<=31 fma, replaces scan_b)
        T = F[((size_t)b * NCHUNK + j) * ACTC + c] + aL * T;
    const unsigned short* p = xnb + ((size_t)(b * LL + k * LC)) * DIMC + c;
    unsigned short*       q = hs  + ((size_t)(b * LL + k * LC)) * ACTC + c;
    float h = T;
    for (int l = 0; l < LC; ++l) {
        h = a * h + bt * bf2f(p[(size_t)l * DIMC]);
        q[(size_t)l * ACTC] = f2bf(h);
    }
}

// ---------------- 128x128 MFMA GEMM ----------------
// MODE 0: +bias, +concat residual (hs | xnb), bf16 out
// MODE 3: +bias, +bf16 add, +f32 add, f32 out
// MODE 4: interleaved-GLU. B = w12 (N=2048, rows 2n=W1[n], 2n+1=W2[n]). Single-acc main
//         loop (the proven (256,4) config). Epilogue pairs adjacent cols via
//         __shfl_xor(u,1): col 2q -> sigmoid, col 2q+1 -> tanh, product is output col q
//         (+ y1 residual). Exact f32 math, identical to the old dual-acc epilogue.
#define TM 128
#define TN 128
#define BK 64

#define GLOAD_LDS(gp, lp) \
    __builtin_amdgcn_global_load_lds((const __attribute__((address_space(1))) unsigned int*)(gp), \
                                     (__attribute__((address_space(3))) unsigned int*)(lp), 16, 0, 0)

template<int MODE>
__global__ __launch_bounds__(256, 4) void k_gemm(
        const unsigned short* __restrict__ A,
        const unsigned short* __restrict__ B0,
        const float* __restrict__ bias0,
        const float* __restrict__ bias1,
        const unsigned short* __restrict__ add0,
        const unsigned short* __restrict__ add1,
        const float* __restrict__ addf,
        float* __restrict__ outf,
        unsigned short* __restrict__ outb,
        int M, int N, int K)
{
    __shared__ __align__(16) char lds[32768];
    unsigned short* sA  = (unsigned short*)lds;
    unsigned short* sB0 = (unsigned short*)(lds + 16384);

    int nx = gridDim.x;
    int bid = blockIdx.y * nx + blockIdx.x;
    int xcd = bid & 7, s = bid >> 3;
    int colt = s % nx, rowgrp = s / nx;
    int m0 = (rowgrp * 8 + xcd) * TM;
    int n0 = colt * TN;

    int t = threadIdx.x;
    int w = t >> 6, lane = t & 63;
    int wm = (w >> 1) * 64, wn = (w & 1) * 64;
    int quad = lane >> 4, lm = lane & 15;
    int lm7 = lm & 7;

    f32x4 zero = {0.f, 0.f, 0.f, 0.f};
    f32x4 acc0[4][4];
#pragma unroll
    for (int i = 0; i < 4; ++i)
#pragma unroll
        for (int j = 0; j < 4; ++j) acc0[i][j] = zero;

    for (int k0 = 0; k0 < K; k0 += BK) {
        __syncthreads();
#pragma unroll
        for (int c = 0; c < 4; ++c) {
            int i = t + c * 256;
            int r = i >> 3;
            int sc = ((i & 7) ^ (r & 7)) << 3;   // swizzled source k-group
            GLOAD_LDS(A  + (size_t)(m0 + r) * K + k0 + sc, sA  + i * 8);
            GLOAD_LDS(B0 + (size_t)(n0 + r) * K + k0 + sc, sB0 + i * 8);
        }
        __syncthreads();

#pragma unroll
        for (int ks = 0; ks < BK; ks += 32) {
            int cgb = ks >> 3;   // 0 or 4
            bf16x8 af[4], b0f[4];
#pragma unroll
            for (int i = 0; i < 4; ++i) {
                int sg = ((cgb + quad) ^ lm7) << 3;
                af[i]  = *(const bf16x8*)(sA  + (wm + i * 16 + lm) * BK + sg);
                b0f[i] = *(const bf16x8*)(sB0 + (wn + i * 16 + lm) * BK + sg);
            }
#pragma unroll
            for (int mi = 0; mi < 4; ++mi)
#pragma unroll
                for (int ni = 0; ni < 4; ++ni)
                    acc0[mi][ni] = __builtin_amdgcn_mfma_f32_16x16x32_bf16(af[mi], b0f[ni], acc0[mi][ni], 0, 0, 0);
        }
    }

    __syncthreads();
    if constexpr (MODE == 3) {
        // fp32 out: two 64-row halves within 32 KB LDS; adds done coalesced at store
        float* sO = (float*)lds;
#pragma unroll
        for (int half = 0; half < 2; ++half) {
            if (wm == half * 64) {
#pragma unroll
                for (int mi = 0; mi < 4; ++mi) {
#pragma unroll
                    for (int ni = 0; ni < 4; ++ni) {
                        int nl = wn + ni * 16 + lm;
                        float bn = bias0[n0 + nl];
#pragma unroll
                        for (int j = 0; j < 4; ++j) {
                            int mloc = mi * 16 + quad * 4 + j;   // 0..63
                            sO[mloc * TN + nl] = acc0[mi][ni][j] + bn;
                        }
                    }
                }
            }
            __syncthreads();
#pragma unroll
            for (int c = 0; c < 8; ++c) {
                int i = t + c * 256;
                int r = i >> 5, c4 = (i & 31) << 2;
                int m = m0 + half * 64 + r, n = n0 + c4;
                float4 v  = *(float4*)(sO + r * TN + c4);
                uint2  ab = *(const uint2*)(add0 + (size_t)m * N + n);
                float4 xf = *(const float4*)(addf + (size_t)m * N + n);
                float4 o;
                o.x = v.x + bf2f((unsigned short)(ab.x & 0xffff)) + xf.x;
                o.y = v.y + bf2f((unsigned short)(ab.x >> 16))    + xf.y;
                o.z = v.z + bf2f((unsigned short)(ab.y & 0xffff)) + xf.z;
                o.w = v.w + bf2f((unsigned short)(ab.y >> 16))    + xf.w;
                *(float4*)(outf + (size_t)m * N + n) = o;
            }
            __syncthreads();
        }
    } else if constexpr (MODE == 4) {
        // GLU pair epilogue: output tile [128][64] bf16
        unsigned short* sO = (unsigned short*)lds;
#pragma unroll
        for (int mi = 0; mi < 4; ++mi) {
#pragma unroll
            for (int ni = 0; ni < 4; ++ni) {
                int nl = wn + ni * 16 + lm;
                int ng = n0 + nl;
                float bn = (nl & 1) ? bias1[ng >> 1] : bias0[ng >> 1];
#pragma unroll
                for (int j = 0; j < 4; ++j) {
                    int ml = wm + mi * 16 + quad * 4 + j;
                    float u  = acc0[mi][ni][j] + bn;
                    float uo = __shfl_xor(u, 1, 64);   // pair partner (adjacent col = adjacent lane)
                    float ue = (nl & 1) ? uo : u;      // even col -> sigmoid arg
                    float ut = (nl & 1) ? u  : uo;     // odd col  -> tanh arg
                    float r = fast_sigmoid(ue) * fast_tanh(ut);
                    if (!(nl & 1)) sO[ml * 64 + (nl >> 1)] = f2bf(r);
                }
            }
        }
        __syncthreads();
#pragma unroll
        for (int c = 0; c < 4; ++c) {
            int i = t + c * 256;
            int r = i >> 3, c8 = (i & 7) << 3;
            int m = m0 + r, n = (n0 >> 1) + c8;      // output cols = N/2, stride DIMC
            uint4 g  = *(uint4*)(sO + r * 64 + c8);
            uint4 av = *(const uint4*)(add0 + (size_t)m * DIMC + n);
            unsigned* gp = (unsigned*)&g;
            unsigned* ap = (unsigned*)&av;
            uint4 o; unsigned* op = (unsigned*)&o;
#pragma unroll
            for (int q = 0; q < 4; ++q) {
                float lo = bf2f((unsigned short)(gp[q] & 0xffff)) + bf2f((unsigned short)(ap[q] & 0xffff));
                float hi = bf2f((unsigned short)(gp[q] >> 16))    + bf2f((unsigned short)(ap[q] >> 16));
                op[q] = (unsigned)f2bf(lo) | ((unsigned)f2bf(hi) << 16);
            }
            *(uint4*)(outb + (size_t)m * DIMC + n) = o;
        }
    } else {
        unsigned short* sO = (unsigned short*)lds;
#pragma unroll
        for (int mi = 0; mi < 4; ++mi) {
#pragma unroll
            for (int ni = 0; ni < 4; ++ni) {
                int nl = wn + ni * 16 + lm;
                int n  = n0 + nl;
                float bn = bias0[n];
#pragma unroll
                for (int j = 0; j < 4; ++j) {
                    int ml = wm + mi * 16 + quad * 4 + j;
                    float v = acc0[mi][ni][j];
                    float r;
                    if constexpr (MODE == 0) {
                        r = v + bn;                       // residual added at store
                    } else { // MODE 2
                        float u = v + bn;
                        r = 0.5f * u * (1.0f + erff(u * 0.70710678118654752f));
                    }
                    sO[ml * TN + nl] = f2bf(r);
                }
            }
        }
        __syncthreads();
#pragma unroll
        for (int c = 0; c < 8; ++c) {
            int i = t + c * 256;
            int r = i >> 4, c8 = (i & 15) << 3;
            int m = m0 + r, n = n0 + c8;
            uint4 g = *(uint4*)(sO + r * TN + c8);
            if constexpr (MODE == 2) {
                *(uint4*)(outb + (size_t)m * N + n) = g;
            } else {
                uint4 av = (n0 < ACTC) ? *(const uint4*)(add0 + (size_t)m * ACTC + n)
                                       : *(const uint4*)(add1 + (size_t)m * DIMC + n);
                unsigned* gp = (unsigned*)&g;
                unsigned* ap = (unsigned*)&av;
                uint4 o;
                unsigned* op = (unsigned*)&o;
#pragma unroll
                for (int q = 0; q < 4; ++q) {
                    float lo = bf2f((unsigned short)(gp[q] & 0xffff)) + bf2f((unsigned short)(ap[q] & 0xffff));
                    float hi = bf2f((unsigned short)(gp[q] >> 16))    + bf2f((unsigned short)(ap[q] >> 16));
                    op[q] = (unsigned)f2bf(lo) | ((unsigned)f2bf(hi) << 16);
                }
                *(uint4*)(outb + (size_t)m * N + n) = o;
            }
        }
    }
}

// ---------------- 128x64-tile GEMM (MODE 2: down-proj + gelu) ----------------
template<int MODE>
__global__ __launch_bounds__(256, 4) void k_gemm64(
        const unsigned short* __restrict__ A,
        const unsigned short* __restrict__ B0,
        const float* __restrict__ bias0,
        unsigned short* __restrict__ outb,
        int M, int N, int K)
{
    __shared__ __align__(16) char lds[24576];
    unsigned short* sA  = (unsigned short*)lds;                  // 128x64 = 16KB
    unsigned short* sB0 = (unsigned short*)(lds + 16384);        // 64x64  =  8KB

    int nx = gridDim.x;
    int bid = blockIdx.y * nx + blockIdx.x;
    int xcd = bid & 7, s = bid >> 3;
    int colt = s % nx, rowgrp = s / nx;
    int m0 = (rowgrp * 8 + xcd) * TM;
    int n0 = colt * 64;

    int t = threadIdx.x;
    int w = t >> 6, lane = t & 63;
    int wm = (w >> 1) * 64, wn = (w & 1) * 32;   // 2x2 wave grid: 64 rows x 32 cols each
    int quad = lane >> 4, lm = lane & 15;
    int lm7 = lm & 7;

    f32x4 zero = {0.f, 0.f, 0.f, 0.f};
    f32x4 acc0[4][2];
#pragma unroll
    for (int i = 0; i < 4; ++i)
#pragma unroll
        for (int j = 0; j < 2; ++j) acc0[i][j] = zero;

    for (int k0 = 0; k0 < K; k0 += BK) {
        __syncthreads();
#pragma unroll
        for (int c = 0; c < 4; ++c) {            // A: 128 rows, 4 rounds
            int i = t + c * 256;
            int r = i >> 3;
            int sc = ((i & 7) ^ (r & 7)) << 3;
            GLOAD_LDS(A + (size_t)(m0 + r) * K + k0 + sc, sA + i * 8);
        }
#pragma unroll
        for (int c = 0; c < 2; ++c) {            // B: 64 rows, 2 rounds
            int i = t + c * 256;
            int r = i >> 3;
            int sc = ((i & 7) ^ (r & 7)) << 3;
            GLOAD_LDS(B0 + (size_t)(n0 + r) * K + k0 + sc, sB0 + i * 8);
        }
        __syncthreads();

#pragma unroll
        for (int ks = 0; ks < BK; ks += 32) {
            int cgb = ks >> 3;   // 0 or 4
            int sg = ((cgb + quad) ^ lm7) << 3;
            bf16x8 af[4], b0f[2];
#pragma unroll
            for (int i = 0; i < 4; ++i)
                af[i] = *(const bf16x8*)(sA + (wm + i * 16 + lm) * BK + sg);
#pragma unroll
            for (int i = 0; i < 2; ++i)
                b0f[i] = *(const bf16x8*)(sB0 + (wn + i * 16 + lm) * BK + sg);
#pragma unroll
            for (int mi = 0; mi < 4; ++mi)
#pragma unroll
                for (int ni = 0; ni < 2; ++ni)
                    acc0[mi][ni] = __builtin_amdgcn_mfma_f32_16x16x32_bf16(af[mi], b0f[ni], acc0[mi][ni], 0, 0, 0);
        }
    }

    // epilogue: acc -> bf16 LDS pack [128][64] -> coalesced store
    __syncthreads();
    unsigned short* sO = (unsigned short*)lds;
#pragma unroll
    for (int mi = 0; mi < 4; ++mi) {
#pragma unroll
        for (int ni = 0; ni < 2; ++ni) {
            int nl = wn + ni * 16 + lm;
            int n  = n0 + nl;
            float bn = bias0[n];
#pragma unroll
            for (int j = 0; j < 4; ++j) {
                int ml = wm + mi * 16 + quad * 4 + j;
                float u = acc0[mi][ni][j] + bn;
                float r = 0.5f * u * (1.0f + erff(u * 0.70710678118654752f));
                sO[ml * 64 + nl] = f2bf(r);
            }
        }
    }
    __syncthreads();
#pragma unroll
    for (int c = 0; c < 4; ++c) {
        int i = t + c * 256;
        int r = i >> 3, c8 = (i & 7) << 3;
        int m = m0 + r, n = n0 + c8;
        uint4 g = *(uint4*)(sO + r * 64 + c8);
        *(uint4*)(outb + (size_t)m * N + n) = g;
    }
}

extern "C" void kernel_launch(void* const* d_in, const int* in_sizes, int n_in,
                              void* d_out, int out_size, void* d_ws, size_t ws_size,
                              hipStream_t stream) {
    (void)in_sizes; (void)n_in; (void)out_size; (void)ws_size;
    const float* x      = (const float*)d_in[0];
    const float* norm_w = (const float*)d_in[1];
    const float* dw_w   = (const float*)d_in[2];
    const float* dw_b   = (const float*)d_in[3];
    const float* pw_w   = (const float*)d_in[4];
    const float* pw_b   = (const float*)d_in[5];
    const float* alpha  = (const float*)d_in[6];
    const float* beta   = (const float*)d_in[7];
    const float* W1_w   = (const float*)d_in[8];
    const float* W1_b   = (const float*)d_in[9];
    const float* W2_w   = (const float*)d_in[10];
    const float* W2_b   = (const float*)d_in[11];
    const float* down_w = (const float*)d_in[12];
    const float* down_b = (const float*)d_in[13];
    const float* up_w   = (const float*)d_in[14];
    const float* up_b   = (const float*)d_in[15];

    char* ws = (char*)d_ws;
    unsigned short* xnb  = (unsigned short*)(ws);
    unsigned short* xc   = (unsigned short*)(ws + 33554432ull);
    unsigned short* hs   = (unsigned short*)(ws + 67108864ull);
    unsigned short* y1b  = (unsigned short*)(ws + 75497472ull);
    unsigned short* y2b  = (unsigned short*)(ws + 109051904ull);
    unsigned short* gact = (unsigned short*)(ws + 142606336ull);
    unsigned short* wpw  = (unsigned short*)(ws + 150994944ull);
    unsigned short* w12  = wpw + 1048576;     // 2048x1024 bf16 (W1/W2 row-interleaved)
    unsigned short* wdn  = wpw + 3145728;
    unsigned short* wup  = wdn + 262144;
    float*          Fb   = (float*)(ws + 159383552ull);

    k_convert5<<<14336, 256, 0, stream>>>(pw_w, W1_w, W2_w, down_w, up_w,
                                          wpw, w12, wdn, wup);

    k_normconv<<<BB * 64, 256, 0, stream>>>(x, norm_w, dw_w, dw_b, xnb, xc);

    k_scan_a<<<BB * NCHUNK, ACTC, 0, stream>>>(xnb, alpha, beta, Fb);
    k_scan_c<<<BB * NCHUNK, ACTC, 0, stream>>>(xnb, alpha, beta, Fb, hs);

    dim3 g0(DIMC / TN, MROWS / TM);          // (8, 128)  = 1024 blocks
    dim3 g1(2 * DIMC / TN, MROWS / TM);      // (16, 128) = 2048 blocks (N=2048 interleaved)
    dim3 g2(HIDC / 64, MROWS / TM);          // (4, 128)  = 512 blocks
    k_gemm<0><<<g0, 256, 0, stream>>>(xc, wpw, pw_b, nullptr, hs, xnb, nullptr, nullptr, y1b, MROWS, DIMC, DIMC);
    k_gemm<4><<<g1, 256, 0, stream>>>(y1b, w12, W1_b, W2_b, y1b, nullptr, nullptr, nullptr, y2b, MROWS, 2 * DIMC, DIMC);
    k_gemm64<2><<<g2, 256, 0, stream>>>(y2b, wdn, down_b, gact, MROWS, HIDC, DIMC);
    k_gemm<3><<<g0, 256, 0, stream>>>(gact, wup, up_b, nullptr, y2b, nullptr, x, (float*)d_out, nullptr, MROWS, DIMC, HIDC);
}

// Round 5
// 349.452 us; speedup vs baseline: 1.0868x; 1.0662x over previous
//
#include <hip/hip_runtime.h>
#include <math.h>

#define DIMC 1024
#define BB   8
#define LL   2048
#define ACTC 256
#define HIDC 256
#define EPSV 1e-6f
#define MROWS (BB * LL)   // 16384
#define NCHUNK 32
#define LC     64         // LL / NCHUNK

typedef __bf16 bf16x8 __attribute__((ext_vector_type(8)));
typedef float  f32x4  __attribute__((ext_vector_type(4)));

__device__ __forceinline__ unsigned short f2bf(float f) {
    union { float f; unsigned int u; } v; v.f = f;
    unsigned int u = v.u + 0x7fffu + ((v.u >> 16) & 1u);
    return (unsigned short)(u >> 16);
}
__device__ __forceinline__ float bf2f(unsigned short s) {
    union { float f; unsigned int u; } v; v.u = ((unsigned int)s) << 16;
    return v.f;
}
// inf-safe fast sigmoid/tanh on native v_exp_f32
__device__ __forceinline__ float fast_sigmoid(float x) {
    return 1.0f / (1.0f + __expf(-x));
}
__device__ __forceinline__ float fast_tanh(float x) {
    float ax = fabsf(x);
    float t = 1.0f - 2.0f / (__expf(2.0f * ax) + 1.0f);  // exp(inf)->inf -> t=1
    return copysignf(t, x);
}

// ---------------- weight convert: all 5 weights in one launch ----------------
__global__ void k_convert5(const float* __restrict__ s0, const float* __restrict__ s1,
                           const float* __restrict__ s2, const float* __restrict__ s3,
                           const float* __restrict__ s4,
                           unsigned short* __restrict__ d0, unsigned short* __restrict__ d1,
                           unsigned short* __restrict__ d2, unsigned short* __restrict__ d3,
                           unsigned short* __restrict__ d4) {
    int i = blockIdx.x * blockDim.x + threadIdx.x;  // total 3670016
    if (i < 1048576)            d0[i]           = f2bf(s0[i]);
    else if (i < 2097152)       d1[i - 1048576] = f2bf(s1[i - 1048576]);
    else if (i < 3145728)       d2[i - 2097152] = f2bf(s2[i - 2097152]);
    else if (i < 3407872)       d3[i - 3145728] = f2bf(s3[i - 3145728]);
    else if (i < 3670016)       d4[i - 3407872] = f2bf(s4[i - 3407872]);
}

// ---------------- fused RMSNorm + depthwise conv (strip of 32 rows + 2-row halo) ----------------
// Pass 1: wave-per-row rms (butterfly shfl, no barriers), xn -> LDS (+ global xnb for
// owned rows). OOR halo rows are written as exact zeros -> zero-padding is free in pass 2.
// Pass 2: K=5 conv reading xn from LDS only; writes xc.
__global__ __launch_bounds__(256, 2) void k_normconv(
        const float* __restrict__ x, const float* __restrict__ w,
        const float* __restrict__ dww, const float* __restrict__ dwb,
        unsigned short* __restrict__ xnb, unsigned short* __restrict__ xc) {
    __shared__ unsigned short sxn[36 * 1024];   // 72 KiB: rows l0-2 .. l0+33
    int blk = blockIdx.x;
    int b = blk >> 6, s = blk & 63;
    int l0 = s * 32;
    int t = threadIdx.x;
    int lane = t & 63, wid = t >> 6;

    float4 nw[4];
#pragma unroll
    for (int j = 0; j < 4; ++j) nw[j] = ((const float4*)w)[j * 64 + lane];

    for (int rr = wid; rr < 36; rr += 4) {
        int l = l0 - 2 + rr;
        bool inr = (l >= 0 && l < LL);
        float4 v[4];
#pragma unroll
        for (int j = 0; j < 4; ++j) { v[j].x = 0.f; v[j].y = 0.f; v[j].z = 0.f; v[j].w = 0.f; }
        if (inr) {
            const float4* xp = (const float4*)(x + ((size_t)b * LL + l) * DIMC);
#pragma unroll
            for (int j = 0; j < 4; ++j) v[j] = xp[j * 64 + lane];
        }
        float ss = 0.f;
#pragma unroll
        for (int j = 0; j < 4; ++j)
            ss += v[j].x * v[j].x + v[j].y * v[j].y + v[j].z * v[j].z + v[j].w * v[j].w;
#pragma unroll
        for (int off = 1; off < 64; off <<= 1) ss += __shfl_xor(ss, off, 64);
        float rinv = 1.0f / sqrtf(ss * (1.0f / DIMC) + EPSV);
#pragma unroll
        for (int j = 0; j < 4; ++j) {
            uint2 o;
            o.x = (unsigned)f2bf(nw[j].x * v[j].x * rinv) | ((unsigned)f2bf(nw[j].y * v[j].y * rinv) << 16);
            o.y = (unsigned)f2bf(nw[j].z * v[j].z * rinv) | ((unsigned)f2bf(nw[j].w * v[j].w * rinv) << 16);
            ((uint2*)(sxn + rr * 1024))[j * 64 + lane] = o;
            if (inr && rr >= 2 && rr < 34)
                ((uint2*)(xnb + ((size_t)b * LL + l) * DIMC))[j * 64 + lane] = o;
        }
    }
    __syncthreads();

    float wgt[4][5];
    int c0 = t * 4;
#pragma unroll
    for (int j = 0; j < 4; ++j)
#pragma unroll
        for (int k = 0; k < 5; ++k) wgt[j][k] = dww[(c0 + j) * 5 + k];
    float4 bv = ((const float4*)dwb)[t];
    for (int r = 0; r < 32; ++r) {
        float acc[4] = {bv.x, bv.y, bv.z, bv.w};
#pragma unroll
        for (int k = 0; k < 5; ++k) {
            uint2 rv = ((const uint2*)(sxn + (r + k) * 1024))[t];
            acc[0] += bf2f((unsigned short)(rv.x & 0xffff)) * wgt[0][k];
            acc[1] += bf2f((unsigned short)(rv.x >> 16))    * wgt[1][k];
            acc[2] += bf2f((unsigned short)(rv.y & 0xffff)) * wgt[2][k];
            acc[3] += bf2f((unsigned short)(rv.y >> 16))    * wgt[3][k];
        }
        uint2 o;
        o.x = (unsigned)f2bf(acc[0]) | ((unsigned)f2bf(acc[1]) << 16);
        o.y = (unsigned)f2bf(acc[2]) | ((unsigned)f2bf(acc[3]) << 16);
        ((uint2*)(xc + ((size_t)b * LL + l0 + r) * DIMC))[t] = o;
    }
}

// ---------------- chunked parallel scan (carry folded into pass c) ----------------
__global__ __launch_bounds__(256) void k_scan_a(const unsigned short* __restrict__ xnb,
                                                const float* __restrict__ alpha,
                                                const float* __restrict__ beta,
                                                float* __restrict__ F) {
    int blk = blockIdx.x;        // b*NCHUNK + k
    int b = blk >> 5, k = blk & (NCHUNK - 1);
    int c = threadIdx.x;
    float a = alpha[c], bt = beta[c];
    const unsigned short* p = xnb + ((size_t)(b * LL + k * LC)) * DIMC + c;
    float h = 0.0f;
    for (int l = 0; l < LC; ++l) h = a * h + bt * bf2f(p[(size_t)l * DIMC]);
    F[(size_t)blk * ACTC + c] = h;
}
__global__ __launch_bounds__(256) void k_scan_c(const unsigned short* __restrict__ xnb,
                                                const float* __restrict__ alpha,
                                                const float* __restrict__ beta,
                                                const float* __restrict__ F,
                                                unsigned short* __restrict__ hs) {
    int blk = blockIdx.x;
    int b = blk >> 5, k = blk & (NCHUNK - 1);
    int c = threadIdx.x;
    float a = alpha[c], bt = beta[c];
    float aL = a;
#pragma unroll
    for (int i = 0; i < 6; ++i) aL *= aL;   // a^64
    float T = 0.0f;
    for (int j = 0; j < k; ++j)             // recompute chunk carry (<=31 fma, replaces scan_b)
        T = F[((size_t)b * NCHUNK + j) * ACTC + c] + aL * T;
    const unsigned short* p = xnb + ((size_t)(b * LL + k * LC)) * DIMC + c;
    unsigned short*       q = hs  + ((size_t)(b * LL + k * LC)) * ACTC + c;
    float h = T;
    for (int l = 0; l < LC; ++l) {
        h = a * h + bt * bf2f(p[(size_t)l * DIMC]);
        q[(size_t)l * ACTC] = f2bf(h);
    }
}

// ---------------- 128x128 MFMA GEMM body (legacy proven structure) ----------------
// MODE 0: +bias, +concat residual (hs | xnb), bf16 out
// MODE 1: dual-B GLU (sigmoid*tanh) + y1 residual, bf16 out
// MODE 3: +bias, +bf16 add, +f32 add, f32 out
// Instantiated via DISTINCTLY NAMED wrapper kernels so rocprof attributes per-mode time.
#define TM 128
#define TN 128
#define BK 64

#define GLOAD_LDS(gp, lp) \
    __builtin_amdgcn_global_load_lds((const __attribute__((address_space(1))) unsigned int*)(gp), \
                                     (__attribute__((address_space(3))) unsigned int*)(lp), 16, 0, 0)

template<int MODE>
__device__ __forceinline__ void gemm_body(
        const unsigned short* __restrict__ A,
        const unsigned short* __restrict__ B0,
        const unsigned short* __restrict__ B1,
        const float* __restrict__ bias0,
        const float* __restrict__ bias1,
        const unsigned short* __restrict__ add0,
        const unsigned short* __restrict__ add1,
        const float* __restrict__ addf,
        float* __restrict__ outf,
        unsigned short* __restrict__ outb,
        int M, int N, int K)
{
    constexpr int LDSB = (MODE == 1) ? 49152 : 32768;
    __shared__ __align__(16) char lds[LDSB];
    unsigned short* sA  = (unsigned short*)lds;
    unsigned short* sB0 = (unsigned short*)(lds + 16384);
    unsigned short* sB1 = (unsigned short*)(lds + 32768);

    int nx = gridDim.x;
    int bid = blockIdx.y * nx + blockIdx.x;
    int xcd = bid & 7, s = bid >> 3;
    int colt = s % nx, rowgrp = s / nx;
    int m0 = (rowgrp * 8 + xcd) * TM;
    int n0 = colt * TN;

    int t = threadIdx.x;
    int w = t >> 6, lane = t & 63;
    int wm = (w >> 1) * 64, wn = (w & 1) * 64;
    int quad = lane >> 4, lm = lane & 15;
    int lm7 = lm & 7;

    f32x4 zero = {0.f, 0.f, 0.f, 0.f};
    f32x4 acc0[4][4];
    f32x4 acc1[(MODE == 1) ? 4 : 1][(MODE == 1) ? 4 : 1];
#pragma unroll
    for (int i = 0; i < 4; ++i)
#pragma unroll
        for (int j = 0; j < 4; ++j) acc0[i][j] = zero;
    if constexpr (MODE == 1) {
#pragma unroll
        for (int i = 0; i < 4; ++i)
#pragma unroll
            for (int j = 0; j < 4; ++j) acc1[i][j] = zero;
    }

    for (int k0 = 0; k0 < K; k0 += BK) {
        __syncthreads();
#pragma unroll
        for (int c = 0; c < 4; ++c) {
            int i = t + c * 256;
            int r = i >> 3;
            int sc = ((i & 7) ^ (r & 7)) << 3;   // swizzled source k-group
            GLOAD_LDS(A  + (size_t)(m0 + r) * K + k0 + sc, sA  + i * 8);
            GLOAD_LDS(B0 + (size_t)(n0 + r) * K + k0 + sc, sB0 + i * 8);
            if constexpr (MODE == 1)
                GLOAD_LDS(B1 + (size_t)(n0 + r) * K + k0 + sc, sB1 + i * 8);
        }
        __syncthreads();

#pragma unroll
        for (int ks = 0; ks < BK; ks += 32) {
            int cgb = ks >> 3;   // 0 or 4
            bf16x8 af[4], b0f[4];
#pragma unroll
            for (int i = 0; i < 4; ++i) {
                int sg = ((cgb + quad) ^ lm7) << 3;
                af[i]  = *(const bf16x8*)(sA  + (wm + i * 16 + lm) * BK + sg);
                b0f[i] = *(const bf16x8*)(sB0 + (wn + i * 16 + lm) * BK + sg);
            }
            if constexpr (MODE == 1) {
                bf16x8 b1f[4];
#pragma unroll
                for (int i = 0; i < 4; ++i)
                    b1f[i] = *(const bf16x8*)(sB1 + (wn + i * 16 + lm) * BK + (((cgb + quad) ^ lm7) << 3));
#pragma unroll
                for (int mi = 0; mi < 4; ++mi)
#pragma unroll
                    for (int ni = 0; ni < 4; ++ni) {
                        acc0[mi][ni] = __builtin_amdgcn_mfma_f32_16x16x32_bf16(af[mi], b0f[ni], acc0[mi][ni], 0, 0, 0);
                        acc1[mi][ni] = __builtin_amdgcn_mfma_f32_16x16x32_bf16(af[mi], b1f[ni], acc1[mi][ni], 0, 0, 0);
                    }
            } else {
#pragma unroll
                for (int mi = 0; mi < 4; ++mi)
#pragma unroll
                    for (int ni = 0; ni < 4; ++ni)
                        acc0[mi][ni] = __builtin_amdgcn_mfma_f32_16x16x32_bf16(af[mi], b0f[ni], acc0[mi][ni], 0, 0, 0);
            }
        }
    }

    __syncthreads();
    if constexpr (MODE == 3) {
        float* sO = (float*)lds;
#pragma unroll
        for (int half = 0; half < 2; ++half) {
            if (wm == half * 64) {
#pragma unroll
                for (int mi = 0; mi < 4; ++mi) {
#pragma unroll
                    for (int ni = 0; ni < 4; ++ni) {
                        int nl = wn + ni * 16 + lm;
                        float bn = bias0[n0 + nl];
#pragma unroll
                        for (int j = 0; j < 4; ++j) {
                            int mloc = mi * 16 + quad * 4 + j;   // 0..63
                            sO[mloc * TN + nl] = acc0[mi][ni][j] + bn;
                        }
                    }
                }
            }
            __syncthreads();
#pragma unroll
            for (int c = 0; c < 8; ++c) {
                int i = t + c * 256;
                int r = i >> 5, c4 = (i & 31) << 2;
                int m = m0 + half * 64 + r, n = n0 + c4;
                float4 v  = *(float4*)(sO + r * TN + c4);
                uint2  ab = *(const uint2*)(add0 + (size_t)m * N + n);
                float4 xf = *(const float4*)(addf + (size_t)m * N + n);
                float4 o;
                o.x = v.x + bf2f((unsigned short)(ab.x & 0xffff)) + xf.x;
                o.y = v.y + bf2f((unsigned short)(ab.x >> 16))    + xf.y;
                o.z = v.z + bf2f((unsigned short)(ab.y & 0xffff)) + xf.z;
                o.w = v.w + bf2f((unsigned short)(ab.y >> 16))    + xf.w;
                *(float4*)(outf + (size_t)m * N + n) = o;
            }
            __syncthreads();
        }
    } else {
        unsigned short* sO = (unsigned short*)lds;
#pragma unroll
        for (int mi = 0; mi < 4; ++mi) {
#pragma unroll
            for (int ni = 0; ni < 4; ++ni) {
                int nl = wn + ni * 16 + lm;
                int n  = n0 + nl;
                float bn = bias0[n];
                float bn1 = (MODE == 1) ? bias1[n] : 0.0f;
#pragma unroll
                for (int j = 0; j < 4; ++j) {
                    int ml = wm + mi * 16 + quad * 4 + j;
                    float v = acc0[mi][ni][j];
                    float r;
                    if constexpr (MODE == 0) {
                        r = v + bn;                       // residual added at store
                    } else {
                        float u1 = v + bn;
                        float u2 = acc1[mi][ni][j] + bn1;
                        r = fast_sigmoid(u1) * fast_tanh(u2);   // y1 added at store
                    }
                    sO[ml * TN + nl] = f2bf(r);
                }
            }
        }
        __syncthreads();
#pragma unroll
        for (int c = 0; c < 8; ++c) {
            int i = t + c * 256;
            int r = i >> 4, c8 = (i & 15) << 3;
            int m = m0 + r, n = n0 + c8;
            uint4 g = *(uint4*)(sO + r * TN + c8);
            uint4 av;
            if constexpr (MODE == 0) {
                av = (n0 < ACTC) ? *(const uint4*)(add0 + (size_t)m * ACTC + n)
                                 : *(const uint4*)(add1 + (size_t)m * DIMC + n);
            } else {
                av = *(const uint4*)(add0 + (size_t)m * N + n);
            }
            unsigned* gp = (unsigned*)&g;
            unsigned* ap = (unsigned*)&av;
            uint4 o;
            unsigned* op = (unsigned*)&o;
#pragma unroll
            for (int q = 0; q < 4; ++q) {
                float lo = bf2f((unsigned short)(gp[q] & 0xffff)) + bf2f((unsigned short)(ap[q] & 0xffff));
                float hi = bf2f((unsigned short)(gp[q] >> 16))    + bf2f((unsigned short)(ap[q] >> 16));
                op[q] = (unsigned)f2bf(lo) | ((unsigned)f2bf(hi) << 16);
            }
            *(uint4*)(outb + (size_t)m * N + n) = o;
        }
    }
}

// Named wrappers (distinct rocprof rows)
__global__ __launch_bounds__(256, 4) void k_gemm_pw(
        const unsigned short* A, const unsigned short* B0, const float* bias0,
        const unsigned short* add0, const unsigned short* add1, unsigned short* outb,
        int M, int N, int K) {
    gemm_body<0>(A, B0, nullptr, bias0, nullptr, add0, add1, nullptr, nullptr, outb, M, N, K);
}
// NOTE: must stay (256,2) — (256,3) caps VGPRs ~85 and spills dual 4x4 f32x4 accs (R5).
__global__ __launch_bounds__(256, 2) void k_gemm_glu(
        const unsigned short* A, const unsigned short* B0, const unsigned short* B1,
        const float* bias0, const float* bias1, const unsigned short* add0,
        unsigned short* outb, int M, int N, int K) {
    gemm_body<1>(A, B0, B1, bias0, bias1, add0, nullptr, nullptr, nullptr, outb, M, N, K);
}
__global__ __launch_bounds__(256, 4) void k_gemm_up(
        const unsigned short* A, const unsigned short* B0, const float* bias0,
        const unsigned short* add0, const float* addf, float* outf,
        int M, int N, int K) {
    gemm_body<3>(A, B0, nullptr, bias0, nullptr, add0, nullptr, addf, outf, nullptr, M, N, K);
}

// ---------------- 128x64-tile GEMM: down-proj + gelu ----------------
__global__ __launch_bounds__(256, 4) void k_gemm_dn(
        const unsigned short* __restrict__ A,
        const unsigned short* __restrict__ B0,
        const float* __restrict__ bias0,
        unsigned short* __restrict__ outb,
        int M, int N, int K)
{
    __shared__ __align__(16) char lds[24576];
    unsigned short* sA  = (unsigned short*)lds;                  // 128x64 = 16KB
    unsigned short* sB0 = (unsigned short*)(lds + 16384);        // 64x64  =  8KB

    int nx = gridDim.x;
    int bid = blockIdx.y * nx + blockIdx.x;
    int xcd = bid & 7, s = bid >> 3;
    int colt = s % nx, rowgrp = s / nx;
    int m0 = (rowgrp * 8 + xcd) * TM;
    int n0 = colt * 64;

    int t = threadIdx.x;
    int w = t >> 6, lane = t & 63;
    int wm = (w >> 1) * 64, wn = (w & 1) * 32;   // 2x2 wave grid: 64 rows x 32 cols each
    int quad = lane >> 4, lm = lane & 15;
    int lm7 = lm & 7;

    f32x4 zero = {0.f, 0.f, 0.f, 0.f};
    f32x4 acc0[4][2];
#pragma unroll
    for (int i = 0; i < 4; ++i)
#pragma unroll
        for (int j = 0; j < 2; ++j) acc0[i][j] = zero;

    for (int k0 = 0; k0 < K; k0 += BK) {
        __syncthreads();
#pragma unroll
        for (int c = 0; c < 4; ++c) {            // A: 128 rows, 4 rounds
            int i = t + c * 256;
            int r = i >> 3;
            int sc = ((i & 7) ^ (r & 7)) << 3;
            GLOAD_LDS(A + (size_t)(m0 + r) * K + k0 + sc, sA + i * 8);
        }
#pragma unroll
        for (int c = 0; c < 2; ++c) {            // B: 64 rows, 2 rounds
            int i = t + c * 256;
            int r = i >> 3;
            int sc = ((i & 7) ^ (r & 7)) << 3;
            GLOAD_LDS(B0 + (size_t)(n0 + r) * K + k0 + sc, sB0 + i * 8);
        }
        __syncthreads();

#pragma unroll
        for (int ks = 0; ks < BK; ks += 32) {
            int cgb = ks >> 3;   // 0 or 4
            int sg = ((cgb + quad) ^ lm7) << 3;
            bf16x8 af[4], b0f[2];
#pragma unroll
            for (int i = 0; i < 4; ++i)
                af[i] = *(const bf16x8*)(sA + (wm + i * 16 + lm) * BK + sg);
#pragma unroll
            for (int i = 0; i < 2; ++i)
                b0f[i] = *(const bf16x8*)(sB0 + (wn + i * 16 + lm) * BK + sg);
#pragma unroll
            for (int mi = 0; mi < 4; ++mi)
#pragma unroll
                for (int ni = 0; ni < 2; ++ni)
                    acc0[mi][ni] = __builtin_amdgcn_mfma_f32_16x16x32_bf16(af[mi], b0f[ni], acc0[mi][ni], 0, 0, 0);
        }
    }

    // epilogue: acc -> bf16 LDS pack [128][64] -> coalesced store
    __syncthreads();
    unsigned short* sO = (unsigned short*)lds;
#pragma unroll
    for (int mi = 0; mi < 4; ++mi) {
#pragma unroll
        for (int ni = 0; ni < 2; ++ni) {
            int nl = wn + ni * 16 + lm;
            int n  = n0 + nl;
            float bn = bias0[n];
#pragma unroll
            for (int j = 0; j < 4; ++j) {
                int ml = wm + mi * 16 + quad * 4 + j;
                float u = acc0[mi][ni][j] + bn;
                float r = 0.5f * u * (1.0f + erff(u * 0.70710678118654752f));
                sO[ml * 64 + nl] = f2bf(r);
            }
        }
    }
    __syncthreads();
#pragma unroll
    for (int c = 0; c < 4; ++c) {
        int i = t + c * 256;
        int r = i >> 3, c8 = (i & 7) << 3;
        int m = m0 + r, n = n0 + c8;
        uint4 g = *(uint4*)(sO + r * 64 + c8);
        *(uint4*)(outb + (size_t)m * N + n) = g;
    }
}

extern "C" void kernel_launch(void* const* d_in, const int* in_sizes, int n_in,
                              void* d_out, int out_size, void* d_ws, size_t ws_size,
                              hipStream_t stream) {
    (void)in_sizes; (void)n_in; (void)out_size; (void)ws_size;
    const float* x      = (const float*)d_in[0];
    const float* norm_w = (const float*)d_in[1];
    const float* dw_w   = (const float*)d_in[2];
    const float* dw_b   = (const float*)d_in[3];
    const float* pw_w   = (const float*)d_in[4];
    const float* pw_b   = (const float*)d_in[5];
    const float* alpha  = (const float*)d_in[6];
    const float* beta   = (const float*)d_in[7];
    const float* W1_w   = (const float*)d_in[8];
    const float* W1_b   = (const float*)d_in[9];
    const float* W2_w   = (const float*)d_in[10];
    const float* W2_b   = (const float*)d_in[11];
    const float* down_w = (const float*)d_in[12];
    const float* down_b = (const float*)d_in[13];
    const float* up_w   = (const float*)d_in[14];
    const float* up_b   = (const float*)d_in[15];

    char* ws = (char*)d_ws;
    unsigned short* xnb  = (unsigned short*)(ws);
    unsigned short* xc   = (unsigned short*)(ws + 33554432ull);
    unsigned short* hs   = (unsigned short*)(ws + 67108864ull);
    unsigned short* y1b  = (unsigned short*)(ws + 75497472ull);
    unsigned short* y2b  = (unsigned short*)(ws + 109051904ull);
    unsigned short* gact = (unsigned short*)(ws + 142606336ull);
    unsigned short* wpw  = (unsigned short*)(ws + 150994944ull);
    unsigned short* w1b  = wpw + 1048576;
    unsigned short* w2b  = w1b + 1048576;
    unsigned short* wdn  = w2b + 1048576;
    unsigned short* wup  = wdn + 262144;
    float*          Fb   = (float*)(ws + 159383552ull);

    k_convert5<<<14336, 256, 0, stream>>>(pw_w, W1_w, W2_w, down_w, up_w,
                                          wpw, w1b, w2b, wdn, wup);

    k_normconv<<<BB * 64, 256, 0, stream>>>(x, norm_w, dw_w, dw_b, xnb, xc);

    k_scan_a<<<BB * NCHUNK, ACTC, 0, stream>>>(xnb, alpha, beta, Fb);
    k_scan_c<<<BB * NCHUNK, ACTC, 0, stream>>>(xnb, alpha, beta, Fb, hs);

    dim3 g0(DIMC / TN, MROWS / TM);          // (8, 128)  = 1024 blocks
    dim3 g2(HIDC / 64, MROWS / TM);          // (4, 128)  = 512 blocks
    k_gemm_pw <<<g0, 256, 0, stream>>>(xc, wpw, pw_b, hs, xnb, y1b, MROWS, DIMC, DIMC);
    k_gemm_glu<<<g0, 256, 0, stream>>>(y1b, w1b, w2b, W1_b, W2_b, y1b, y2b, MROWS, DIMC, DIMC);
    k_gemm_dn <<<g2, 256, 0, stream>>>(y2b, wdn, down_b, gact, MROWS, HIDC, DIMC);
    k_gemm_up <<<g0, 256, 0, stream>>>(gact, wup, up_b, y2b, x, (float*)d_out, MROWS, DIMC, HIDC);
}